// Round 5
// baseline (496.330 us; speedup 1.0000x reference)
//
#include <hip/hip_runtime.h>

// ---------------------------------------------------------------------------
// BeliefStateWrapper: gather(fi,bi) -> Linear(1024->512)+LeakyReLU ->
// Linear(512->64000) -> per-branch log_softmax NLL -> weighted mean (scalar).
//
// R5: gemm2 VALU diet: explicit ping-pong A-fragment prefetch (no reg
// copies), ballot-gated label extraction (~13% of wave-panels enter the
// compare block), bias folded into exp2 fma. Kernels fused: prep
// (gather+labcol+w1 transpose) and final (strip-reduce + NLL + scalar).
// ---------------------------------------------------------------------------

typedef __bf16 bf16x8 __attribute__((ext_vector_type(8)));
typedef __bf16 bf16x4 __attribute__((ext_vector_type(4)));
typedef float f32x4  __attribute__((ext_vector_type(4)));

#define MFMA16(a, b, c) __builtin_amdgcn_mfma_f32_16x16x32_bf16(a, b, c, 0, 0, 0)

static constexpr int Bsz   = 2;
static constexpr int L     = 512;
static constexpr int D     = 512;
static constexpr int V     = 32000;
static constexpr int K1    = 2 * D;      // 1024
static constexpr int N1    = D;          // 512
static constexpr int K2    = D;          // 512
static constexpr int N2    = 2 * V;      // 64000
static constexpr int NSTRIP = N2 / 64;   // 1000 strips (500 per branch)
static constexpr float LOG2E = 1.44269504088896340736f;

// Apack chunk base (bf16 elems) for (panel, ks, mi); chunk = 64 lanes x 8
// bf16 = 512 elems = 1 KB. Lane l holds A[panel*64+mi*16+(l&15)]
// [ks*32+(l>>4)*8 .. +7].
__device__ __host__ inline size_t apack_chunk(int panel, int ks, int mi) {
    return (((size_t)panel * 16 + ks) * 4 + mi) * 512;
}

// ---------------------------------------------------------------------------
// prep kernel: blocks [0, G1) do gather+cast (+labcol side-task);
// blocks [G1, G1+128) transpose+cast w1 fp32 [1024][512] -> W1T bf16 [512][1024].
// ---------------------------------------------------------------------------
__global__ void prep_kernel(const float* __restrict__ fwd,
                            const float* __restrict__ bwd,
                            const int* __restrict__ fi,
                            const int* __restrict__ bi,
                            const int* __restrict__ seq,
                            const float* __restrict__ w1,
                            __bf16* __restrict__ A1,
                            __bf16* __restrict__ W1T,
                            int* __restrict__ labcol,
                            int N, int M, int Mpad, int G1) {
    __shared__ __align__(16) __bf16 tile[64][68];
    if ((int)blockIdx.x >= G1) {
        // ---- w1 transpose part: bid -> (bx in [0,8), by in [0,16))
        int bid = blockIdx.x - G1;
        int bx = bid & 7, by = bid >> 3;
        int t  = threadIdx.x;
        int tx = t & 15, ty = t >> 4;
        int n0 = bx * 64, k0 = by * 64;
        for (int i = 0; i < 4; i++) {
            int k = k0 + ty + 16 * i;
            float4 v = *(const float4*)(w1 + (size_t)k * N1 + n0 + tx * 4);
            tile[tx * 4 + 0][ty + 16 * i] = (__bf16)v.x;
            tile[tx * 4 + 1][ty + 16 * i] = (__bf16)v.y;
            tile[tx * 4 + 2][ty + 16 * i] = (__bf16)v.z;
            tile[tx * 4 + 3][ty + 16 * i] = (__bf16)v.w;
        }
        __syncthreads();
        for (int i = 0; i < 4; i++) {
            int n = n0 + ty + 16 * i;
            bf16x4 o;
            o[0] = tile[ty + 16 * i][tx * 4 + 0];
            o[1] = tile[ty + 16 * i][tx * 4 + 1];
            o[2] = tile[ty + 16 * i][tx * 4 + 2];
            o[3] = tile[ty + 16 * i][tx * 4 + 3];
            *(bf16x4*)(W1T + (size_t)n * K1 + k0 + tx * 4) = o;
        }
        return;
    }
    int t = blockIdx.x * 256 + threadIdx.x;          // one thread = 8 elems
    // side-task: label columns (Mpad*2 entries)
    if (t < Mpad * 2) {
        int m = t >> 1, br = t & 1;
        if (m >= M) labcol[t] = -1;
        else {
            int b = m / N, n = m - b * N;
            int tok = br ? seq[b * L + bi[n]] : seq[b * L + fi[n]];
            labcol[t] = br * V + tok;
        }
    }
    int total = Mpad * (K1 / 8);
    if (t >= total) return;
    int m  = t >> 7;              // / (1024/8)
    int c8 = (t & 127) * 8;
    bf16x8 out;
    if (m < M) {
        int b = m / N;
        int n = m - b * N;
        const float* src;
        if (c8 < D) src = fwd + ((size_t)(b * L + fi[n])) * D + c8;
        else        src = bwd + ((size_t)(b * L + bi[n])) * D + (c8 - D);
        float4 v0 = *(const float4*)(src);
        float4 v1 = *(const float4*)(src + 4);
        out[0] = (__bf16)v0.x; out[1] = (__bf16)v0.y;
        out[2] = (__bf16)v0.z; out[3] = (__bf16)v0.w;
        out[4] = (__bf16)v1.x; out[5] = (__bf16)v1.y;
        out[6] = (__bf16)v1.z; out[7] = (__bf16)v1.w;
    } else {
        for (int j = 0; j < 8; j++) out[j] = (__bf16)0.0f;
    }
    *(bf16x8*)(A1 + (size_t)m * K1 + c8) = out;
}

// ---------------------------------------------------------------------------
// GEMM1: H = leaky_relu(A1 @ W1 + b1), emitted in Apack fragment-major
// layout.  128x128 tile, 4 waves (2x2), 16x16x32 MFMA, BK=32.  Epilogue
// round-trips C through LDS so the Apack stores are fully coalesced.
// ---------------------------------------------------------------------------
__global__ __launch_bounds__(256) void gemm1_kernel(
        const __bf16* __restrict__ A, const __bf16* __restrict__ Bt,
        const float* __restrict__ bias, __bf16* __restrict__ Apack, int K) {
    __shared__ __align__(16) __bf16 At[128][40];
    __shared__ __align__(16) __bf16 Bl[128][40];
    __shared__ __align__(16) __bf16 Cld[128][136];
    const int t = threadIdx.x;
    const int by = blockIdx.y, bx = blockIdx.x;
    const int m0 = by * 128, n0 = bx * 128;
    const int srow = t >> 2, schunk = (t & 3) * 8;
    const int wave = t >> 6, lane = t & 63;
    const int wrow = (wave >> 1) * 64, wcol = (wave & 1) * 64;
    const int q = lane >> 4, ln = lane & 15;

    f32x4 acc[4][4] = {};
    for (int k0 = 0; k0 < K; k0 += 32) {
        __syncthreads();
        *(bf16x8*)&At[srow][schunk]      = *(const bf16x8*)(A  + (size_t)(m0 + srow)      * K + k0 + schunk);
        *(bf16x8*)&At[srow + 64][schunk] = *(const bf16x8*)(A  + (size_t)(m0 + srow + 64) * K + k0 + schunk);
        *(bf16x8*)&Bl[srow][schunk]      = *(const bf16x8*)(Bt + (size_t)(n0 + srow)      * K + k0 + schunk);
        *(bf16x8*)&Bl[srow + 64][schunk] = *(const bf16x8*)(Bt + (size_t)(n0 + srow + 64) * K + k0 + schunk);
        __syncthreads();
        bf16x8 af[4], bfr[4];
        for (int i = 0; i < 4; i++) af[i]  = *(const bf16x8*)&At[wrow + i * 16 + ln][q * 8];
        for (int i = 0; i < 4; i++) bfr[i] = *(const bf16x8*)&Bl[wcol + i * 16 + ln][q * 8];
        for (int mi = 0; mi < 4; mi++)
            for (int ni = 0; ni < 4; ni++)
                acc[mi][ni] = MFMA16(af[mi], bfr[ni], acc[mi][ni]);
    }
    // bias + leaky -> LDS C tile
    for (int ni = 0; ni < 4; ni++) {
        int gcol = n0 + wcol + ni * 16 + ln;
        float bv = bias[gcol];
        for (int mi = 0; mi < 4; mi++)
            for (int r = 0; r < 4; r++) {
                float v = acc[mi][ni][r] + bv;
                v = v > 0.0f ? v : 0.01f * v;
                Cld[wrow + mi * 16 + q * 4 + r][wcol + ni * 16 + ln] = (__bf16)v;
            }
    }
    __syncthreads();
    // pack out: 32 chunks (pl 0..1, ksl 0..3, mi 0..3), wave w -> c = w+4i
    for (int i = 0; i < 8; i++) {
        int c   = wave + 4 * i;
        int pl  = c >> 4, ksl = (c >> 2) & 3, mi = c & 3;
        int row = pl * 64 + mi * 16 + (lane & 15);
        int col = ksl * 32 + (lane >> 4) * 8;
        bf16x8 v = *(const bf16x8*)&Cld[row][col];
        size_t base = apack_chunk(2 * by + pl, 4 * bx + ksl, mi);
        *(bf16x8*)(Apack + base + lane * 8) = v;
    }
}

// ---------------------------------------------------------------------------
// GEMM2 (persistent 64-col strip, 512 threads = 8 waves, 2 blocks/CU):
// W2 strip staged once fp32->bf16 into fragment-major LDS "Bpack"
// (conflict-free b128 reads; non-temporal global loads so the 131 MB
// stream doesn't evict Apack from L2).  Waves sweep 64-row panels with
// ping-pong A prefetch from L2 (no copies, no barriers).  Epilogue:
// exp2(fma)-rowsum -> shuffle reduce -> coalesced partial store; label
// logit only in ballot-gated rare block.
// ---------------------------------------------------------------------------
__global__ __launch_bounds__(512, 4) void gemm2_kernel(
        const __bf16* __restrict__ Apack, const float* __restrict__ w2,
        const float* __restrict__ b2, const int* __restrict__ labcol,
        float* __restrict__ partial, float* __restrict__ lab, int Mpad) {
    __shared__ __align__(16) __bf16 Bp[64 * 512];   // 64 KB, fragment-major
    const int t = threadIdx.x;
    const int strip = blockIdx.x;
    const int c0 = strip * 64;
    const int branch = (c0 >= V) ? 1 : 0;

    // ---- stage W2 strip fp32 [512][64000] -> Bpack bf16
    {
        const int col = t & 63;
        const int ni = col >> 4, lncol = col & 15;
        const int kb0 = (t >> 6) * 8;
        for (int r = 0; r < 8; r++) {
            int kb = kb0 + r * 64;
            int ks = kb >> 5, qk = (kb >> 3) & 3;
            float v[8];
#pragma unroll
            for (int j = 0; j < 8; j++)
                v[j] = __builtin_nontemporal_load(w2 + (size_t)(kb + j) * N2 + c0 + col);
            bf16x8 o;
#pragma unroll
            for (int j = 0; j < 8; j++) o[j] = (__bf16)v[j];
            *(bf16x8*)&Bp[(size_t)(((ks * 4 + ni) * 64 + qk * 16 + lncol)) * 8] = o;
        }
    }
    __syncthreads();

    const int wave = t >> 6, lane = t & 63;
    const int q = lane >> 4, ln = lane & 15;

    float bvn[4], bvl2[4];
#pragma unroll
    for (int ni = 0; ni < 4; ni++) {
        bvn[ni] = b2[c0 + ni * 16 + ln];
        bvl2[ni] = bvn[ni] * LOG2E;
    }

    const int npanels = Mpad >> 6;
    for (int p = wave; p < npanels; p += 8) {
        const __bf16* base = Apack + apack_chunk(p, 0, 0) + lane * 8;

        f32x4 acc[4][4] = {};
        bf16x8 afA[4], afB[4];
#pragma unroll
        for (int mi = 0; mi < 4; mi++)
            afA[mi] = *(const bf16x8*)(base + mi * 512);
        // ping-pong K loop: 7 full double-steps + peeled tail, no reg copies
#pragma unroll 1
        for (int ks = 0; ks < 14; ks += 2) {
#pragma unroll
            for (int mi = 0; mi < 4; mi++)
                afB[mi] = *(const bf16x8*)(base + (size_t)(ks + 1) * 2048 + mi * 512);
            {
                bf16x8 bf0[4];
#pragma unroll
                for (int ni = 0; ni < 4; ni++)
                    bf0[ni] = *(const bf16x8*)&Bp[(size_t)(ks * 4 + ni) * 512 + lane * 8];
#pragma unroll
                for (int mi = 0; mi < 4; mi++)
#pragma unroll
                    for (int ni = 0; ni < 4; ni++)
                        acc[mi][ni] = MFMA16(afA[mi], bf0[ni], acc[mi][ni]);
            }
#pragma unroll
            for (int mi = 0; mi < 4; mi++)
                afA[mi] = *(const bf16x8*)(base + (size_t)(ks + 2) * 2048 + mi * 512);
            {
                bf16x8 bf1[4];
#pragma unroll
                for (int ni = 0; ni < 4; ni++)
                    bf1[ni] = *(const bf16x8*)&Bp[(size_t)((ks + 1) * 4 + ni) * 512 + lane * 8];
#pragma unroll
                for (int mi = 0; mi < 4; mi++)
#pragma unroll
                    for (int ni = 0; ni < 4; ni++)
                        acc[mi][ni] = MFMA16(afB[mi], bf1[ni], acc[mi][ni]);
            }
        }
        // tail: ks = 14, 15
        {
#pragma unroll
            for (int mi = 0; mi < 4; mi++)
                afB[mi] = *(const bf16x8*)(base + (size_t)15 * 2048 + mi * 512);
            bf16x8 bf0[4];
#pragma unroll
            for (int ni = 0; ni < 4; ni++)
                bf0[ni] = *(const bf16x8*)&Bp[(size_t)(14 * 4 + ni) * 512 + lane * 8];
#pragma unroll
            for (int mi = 0; mi < 4; mi++)
#pragma unroll
                for (int ni = 0; ni < 4; ni++)
                    acc[mi][ni] = MFMA16(afA[mi], bf0[ni], acc[mi][ni]);
            bf16x8 bf1[4];
#pragma unroll
            for (int ni = 0; ni < 4; ni++)
                bf1[ni] = *(const bf16x8*)&Bp[(size_t)(15 * 4 + ni) * 512 + lane * 8];
#pragma unroll
            for (int mi = 0; mi < 4; mi++)
#pragma unroll
                for (int ni = 0; ni < 4; ni++)
                    acc[mi][ni] = MFMA16(afB[mi], bf1[ni], acc[mi][ni]);
        }

        // ---- label columns for this wave's 16 rows; gated rare path
        int lc[4][4];
        bool hit = false;
#pragma unroll
        for (int mi = 0; mi < 4; mi++)
#pragma unroll
            for (int r = 0; r < 4; r++) {
                lc[mi][r] = labcol[(p * 64 + mi * 16 + q * 4 + r) * 2 + branch];
                hit |= ((unsigned)(lc[mi][r] - c0) < 64u);
            }
        if (__any(hit)) {
#pragma unroll
            for (int ni = 0; ni < 4; ni++) {
                const int gcol = c0 + ni * 16 + ln;
#pragma unroll
                for (int mi = 0; mi < 4; mi++)
#pragma unroll
                    for (int r = 0; r < 4; r++)
                        if (gcol == lc[mi][r]) {
                            int gm = p * 64 + mi * 16 + q * 4 + r;
                            lab[gm * 2 + branch] = acc[mi][ni][r] + bvn[ni];
                        }
            }
        }

        // ---- exp2-rowsum epilogue (bias folded into fma)
        float rowsum[4][4];
#pragma unroll
        for (int mi = 0; mi < 4; mi++)
#pragma unroll
            for (int r = 0; r < 4; r++) rowsum[mi][r] = 0.0f;
#pragma unroll
        for (int ni = 0; ni < 4; ni++) {
            const float bl2 = bvl2[ni];
#pragma unroll
            for (int mi = 0; mi < 4; mi++)
#pragma unroll
                for (int r = 0; r < 4; r++)
                    rowsum[mi][r] += __builtin_exp2f(__builtin_fmaf(acc[mi][ni][r], LOG2E, bl2));
        }
        // reduce over the 16 column-lanes (lane bits 0..3)
#pragma unroll
        for (int mi = 0; mi < 4; mi++)
#pragma unroll
            for (int r = 0; r < 4; r++) {
                float s = rowsum[mi][r];
                s += __shfl_xor(s, 1);
                s += __shfl_xor(s, 2);
                s += __shfl_xor(s, 4);
                s += __shfl_xor(s, 8);
                rowsum[mi][r] = s;
            }
        // per-lane row gather: lane l wants row l = mi*16 + q*4 + r; value
        // lives in lanes with q-src = (l>>2)&3 at register rowsum[l>>4][l&3].
        float mine = 0.0f;
        const int srcl = ((lane >> 2) & 3) * 16;
#pragma unroll
        for (int mi2 = 0; mi2 < 4; mi2++)
#pragma unroll
            for (int r2 = 0; r2 < 4; r2++) {
                float tv = __shfl(rowsum[mi2][r2], srcl);
                if ((lane >> 4) == mi2 && (lane & 3) == r2) mine = tv;
            }
        partial[(size_t)strip * Mpad + p * 64 + lane] = mine;
    }
}

// ---------------------------------------------------------------------------
// Fused final: for each (m, branch): sumexp = sum of the branch's 500 strip
// partials; nll = log(sumexp) - lab; weighted block-reduce; atomicAdd into
// out (pre-zeroed by hipMemsetAsync).
// ---------------------------------------------------------------------------
__global__ void final_kernel(const float* __restrict__ partial,
                             const float* __restrict__ lab,
                             float* __restrict__ out, int M, int Mpad) {
    __shared__ float red[4];
    int t = blockIdx.x * 256 + threadIdx.x;
    float acc = 0.0f;
    if (t < 2 * M) {
        int br = (t >= M) ? 1 : 0;
        int m = t - br * M;
        int s0 = br * (NSTRIP / 2), s1 = s0 + NSTRIP / 2;
        float s = 0.0f;
#pragma unroll 4
        for (int si = s0; si < s1; si++)
            s += partial[(size_t)si * Mpad + m];
        float nll = logf(s) - lab[m * 2 + br];
        acc = (br ? 0.25f : 1.0f) * nll;
    }
    acc += __shfl_xor(acc, 32);
    acc += __shfl_xor(acc, 16);
    acc += __shfl_xor(acc, 8);
    acc += __shfl_xor(acc, 4);
    acc += __shfl_xor(acc, 2);
    acc += __shfl_xor(acc, 1);
    int wv = threadIdx.x >> 6, ln = threadIdx.x & 63;
    if (ln == 0) red[wv] = acc;
    __syncthreads();
    if (threadIdx.x == 0)
        atomicAdd(out, (red[0] + red[1] + red[2] + red[3]) / (float)(2 * M));
}

// ---------------------------------------------------------------------------
extern "C" void kernel_launch(void* const* d_in, const int* in_sizes, int n_in,
                              void* d_out, int out_size, void* d_ws, size_t ws_size,
                              hipStream_t stream) {
    const float* fwd = (const float*)d_in[0];
    const float* bwd = (const float*)d_in[1];
    const int*   seq = (const int*)d_in[2];
    const int*   fi  = (const int*)d_in[3];
    const int*   bi  = (const int*)d_in[4];
    const float* w1  = (const float*)d_in[5];
    const float* b1  = (const float*)d_in[6];
    const float* w2  = (const float*)d_in[7];
    const float* b2  = (const float*)d_in[8];
    float* out = (float*)d_out;

    const int N    = in_sizes[3];              // 1303
    const int M    = Bsz * N;                  // 2606
    const int Mpad = ((M + 255) / 256) * 256;  // 2816

    // workspace layout (16B-aligned slices)
    char* ws = (char*)d_ws;
    __bf16* A1    = (__bf16*)(ws);                                   // Mpad*1024
    __bf16* W1T   = (__bf16*)(ws + (size_t)Mpad * K1 * 2);           // 512*1024
    __bf16* Apack = (__bf16*)((char*)W1T + (size_t)N1 * K1 * 2);     // Mpad*512
    float*  partial = (float*)((char*)Apack + (size_t)Mpad * N1 * 2);// NSTRIP*Mpad
    float*  lab     = (float*)((char*)partial + (size_t)NSTRIP * Mpad * 4); // Mpad*2
    int*    labcol  = (int*)((char*)lab + (size_t)Mpad * 2 * 4);     // Mpad*2

    // 1. fused prep: gather+cast (+labcol) and w1 transpose
    {
        int G1 = Mpad * (K1 / 8) / 256;        // gather blocks
        prep_kernel<<<G1 + 128, 256, 0, stream>>>(
            fwd, bwd, fi, bi, seq, w1, A1, W1T, labcol, N, M, Mpad, G1);
    }
    // 2. zero the output accumulator
    hipMemsetAsync(out, 0, sizeof(float), stream);
    // 3. GEMM1 -> Apack (fragment-major H)
    gemm1_kernel<<<dim3(N1 / 128, Mpad / 128), 256, 0, stream>>>(A1, W1T, b1, Apack, K1);
    // 4. GEMM2 persistent strips -> per-strip partial rowsums + labels
    gemm2_kernel<<<NSTRIP, 512, 0, stream>>>(Apack, w2, b2, labcol, partial, lab, Mpad);
    // 5. fused final: strip-reduce + NLL + weighted mean -> out
    final_kernel<<<(2 * M + 255) / 256, 256, 0, stream>>>(partial, lab, out, M, Mpad);
}

// Round 6
// 442.574 us; speedup vs baseline: 1.1215x; 1.1215x over previous
//
#include <hip/hip_runtime.h>

// ---------------------------------------------------------------------------
// BeliefStateWrapper: gather(fi,bi) -> Linear(1024->512)+LeakyReLU ->
// Linear(512->64000) -> per-branch log_softmax NLL -> weighted mean (scalar).
//
// R6: R5's ping-pong spilled (128-reg unified budget at 16 waves/CU: 64 acc
// AGPRs leave only 64 arch VGPRs; afA+afB+bf0+bf1 = 64 alone). Revert gemm2
// to the R4-proven spill-free K-loop; take register-cheap VALU cuts instead:
// branch-split labcol (one int/lane hit test, rare-path reload), exp2-fma
// bias fold, and a parallelized fused final reduce.
// ---------------------------------------------------------------------------

typedef __bf16 bf16x8 __attribute__((ext_vector_type(8)));
typedef __bf16 bf16x4 __attribute__((ext_vector_type(4)));
typedef float f32x4  __attribute__((ext_vector_type(4)));

#define MFMA16(a, b, c) __builtin_amdgcn_mfma_f32_16x16x32_bf16(a, b, c, 0, 0, 0)

static constexpr int Bsz   = 2;
static constexpr int L     = 512;
static constexpr int D     = 512;
static constexpr int V     = 32000;
static constexpr int K1    = 2 * D;      // 1024
static constexpr int N1    = D;          // 512
static constexpr int K2    = D;          // 512
static constexpr int N2    = 2 * V;      // 64000
static constexpr int NSTRIP = N2 / 64;   // 1000 strips (500 per branch)
static constexpr float LOG2E = 1.44269504088896340736f;

// Apack chunk base (bf16 elems) for (panel, ks, mi); chunk = 64 lanes x 8
// bf16 = 512 elems = 1 KB. Lane l holds A[panel*64+mi*16+(l&15)]
// [ks*32+(l>>4)*8 .. +7].
__device__ __host__ inline size_t apack_chunk(int panel, int ks, int mi) {
    return (((size_t)panel * 16 + ks) * 4 + mi) * 512;
}

// ---------------------------------------------------------------------------
// prep kernel: blocks [0, G1) do gather+cast (+labcol side-task, branch-split
// layout labcol[2][Mpad]); blocks [G1, G1+128) transpose+cast w1 -> W1T.
// ---------------------------------------------------------------------------
__global__ void prep_kernel(const float* __restrict__ fwd,
                            const float* __restrict__ bwd,
                            const int* __restrict__ fi,
                            const int* __restrict__ bi,
                            const int* __restrict__ seq,
                            const float* __restrict__ w1,
                            __bf16* __restrict__ A1,
                            __bf16* __restrict__ W1T,
                            int* __restrict__ labcol,
                            int N, int M, int Mpad, int G1) {
    __shared__ __align__(16) __bf16 tile[64][68];
    if ((int)blockIdx.x >= G1) {
        // ---- w1 transpose part: bid -> (bx in [0,8), by in [0,16))
        int bid = blockIdx.x - G1;
        int bx = bid & 7, by = bid >> 3;
        int t  = threadIdx.x;
        int tx = t & 15, ty = t >> 4;
        int n0 = bx * 64, k0 = by * 64;
        for (int i = 0; i < 4; i++) {
            int k = k0 + ty + 16 * i;
            float4 v = *(const float4*)(w1 + (size_t)k * N1 + n0 + tx * 4);
            tile[tx * 4 + 0][ty + 16 * i] = (__bf16)v.x;
            tile[tx * 4 + 1][ty + 16 * i] = (__bf16)v.y;
            tile[tx * 4 + 2][ty + 16 * i] = (__bf16)v.z;
            tile[tx * 4 + 3][ty + 16 * i] = (__bf16)v.w;
        }
        __syncthreads();
        for (int i = 0; i < 4; i++) {
            int n = n0 + ty + 16 * i;
            bf16x4 o;
            o[0] = tile[ty + 16 * i][tx * 4 + 0];
            o[1] = tile[ty + 16 * i][tx * 4 + 1];
            o[2] = tile[ty + 16 * i][tx * 4 + 2];
            o[3] = tile[ty + 16 * i][tx * 4 + 3];
            *(bf16x4*)(W1T + (size_t)n * K1 + k0 + tx * 4) = o;
        }
        return;
    }
    int t = blockIdx.x * 256 + threadIdx.x;          // one thread = 8 elems
    // side-task: label columns, branch-split labcol[br][m]
    if (t < Mpad * 2) {
        int m = t >> 1, br = t & 1;
        if (m >= M) labcol[br * Mpad + m] = -1;
        else {
            int b = m / N, n = m - b * N;
            int tok = br ? seq[b * L + bi[n]] : seq[b * L + fi[n]];
            labcol[br * Mpad + m] = br * V + tok;
        }
    }
    int total = Mpad * (K1 / 8);
    if (t >= total) return;
    int m  = t >> 7;              // / (1024/8)
    int c8 = (t & 127) * 8;
    bf16x8 out;
    if (m < M) {
        int b = m / N;
        int n = m - b * N;
        const float* src;
        if (c8 < D) src = fwd + ((size_t)(b * L + fi[n])) * D + c8;
        else        src = bwd + ((size_t)(b * L + bi[n])) * D + (c8 - D);
        float4 v0 = *(const float4*)(src);
        float4 v1 = *(const float4*)(src + 4);
        out[0] = (__bf16)v0.x; out[1] = (__bf16)v0.y;
        out[2] = (__bf16)v0.z; out[3] = (__bf16)v0.w;
        out[4] = (__bf16)v1.x; out[5] = (__bf16)v1.y;
        out[6] = (__bf16)v1.z; out[7] = (__bf16)v1.w;
    } else {
        for (int j = 0; j < 8; j++) out[j] = (__bf16)0.0f;
    }
    *(bf16x8*)(A1 + (size_t)m * K1 + c8) = out;
}

// ---------------------------------------------------------------------------
// GEMM1: H = leaky_relu(A1 @ W1 + b1), emitted in Apack fragment-major
// layout.  128x128 tile, 4 waves (2x2), 16x16x32 MFMA, BK=32.  Epilogue
// round-trips C through LDS so the Apack stores are fully coalesced.
// ---------------------------------------------------------------------------
__global__ __launch_bounds__(256) void gemm1_kernel(
        const __bf16* __restrict__ A, const __bf16* __restrict__ Bt,
        const float* __restrict__ bias, __bf16* __restrict__ Apack, int K) {
    __shared__ __align__(16) __bf16 At[128][40];
    __shared__ __align__(16) __bf16 Bl[128][40];
    __shared__ __align__(16) __bf16 Cld[128][136];
    const int t = threadIdx.x;
    const int by = blockIdx.y, bx = blockIdx.x;
    const int m0 = by * 128, n0 = bx * 128;
    const int srow = t >> 2, schunk = (t & 3) * 8;
    const int wave = t >> 6, lane = t & 63;
    const int wrow = (wave >> 1) * 64, wcol = (wave & 1) * 64;
    const int q = lane >> 4, ln = lane & 15;

    f32x4 acc[4][4] = {};
    for (int k0 = 0; k0 < K; k0 += 32) {
        __syncthreads();
        *(bf16x8*)&At[srow][schunk]      = *(const bf16x8*)(A  + (size_t)(m0 + srow)      * K + k0 + schunk);
        *(bf16x8*)&At[srow + 64][schunk] = *(const bf16x8*)(A  + (size_t)(m0 + srow + 64) * K + k0 + schunk);
        *(bf16x8*)&Bl[srow][schunk]      = *(const bf16x8*)(Bt + (size_t)(n0 + srow)      * K + k0 + schunk);
        *(bf16x8*)&Bl[srow + 64][schunk] = *(const bf16x8*)(Bt + (size_t)(n0 + srow + 64) * K + k0 + schunk);
        __syncthreads();
        bf16x8 af[4], bfr[4];
        for (int i = 0; i < 4; i++) af[i]  = *(const bf16x8*)&At[wrow + i * 16 + ln][q * 8];
        for (int i = 0; i < 4; i++) bfr[i] = *(const bf16x8*)&Bl[wcol + i * 16 + ln][q * 8];
        for (int mi = 0; mi < 4; mi++)
            for (int ni = 0; ni < 4; ni++)
                acc[mi][ni] = MFMA16(af[mi], bfr[ni], acc[mi][ni]);
    }
    // bias + leaky -> LDS C tile
    for (int ni = 0; ni < 4; ni++) {
        int gcol = n0 + wcol + ni * 16 + ln;
        float bv = bias[gcol];
        for (int mi = 0; mi < 4; mi++)
            for (int r = 0; r < 4; r++) {
                float v = acc[mi][ni][r] + bv;
                v = v > 0.0f ? v : 0.01f * v;
                Cld[wrow + mi * 16 + q * 4 + r][wcol + ni * 16 + ln] = (__bf16)v;
            }
    }
    __syncthreads();
    // pack out: 32 chunks (pl 0..1, ksl 0..3, mi 0..3), wave w -> c = w+4i
    for (int i = 0; i < 8; i++) {
        int c   = wave + 4 * i;
        int pl  = c >> 4, ksl = (c >> 2) & 3, mi = c & 3;
        int row = pl * 64 + mi * 16 + (lane & 15);
        int col = ksl * 32 + (lane >> 4) * 8;
        bf16x8 v = *(const bf16x8*)&Cld[row][col];
        size_t base = apack_chunk(2 * by + pl, 4 * bx + ksl, mi);
        *(bf16x8*)(Apack + base + lane * 8) = v;
    }
}

// ---------------------------------------------------------------------------
// GEMM2 (persistent 64-col strip, 512 threads = 8 waves, 2 blocks/CU):
// W2 strip staged once fp32->bf16 into fragment-major LDS "Bpack"
// (conflict-free b128; non-temporal global loads protect Apack's L2
// residency).  R4-proven spill-free K-loop (prefetch+copy).  Label logit:
// one int/lane hit test + ballot; rare path reloads labcol/b2.  Epilogue:
// exp2(fma)-rowsum -> shuffle reduce -> coalesced partial store.
// ---------------------------------------------------------------------------
__global__ __launch_bounds__(512, 4) void gemm2_kernel(
        const __bf16* __restrict__ Apack, const float* __restrict__ w2,
        const float* __restrict__ b2, const int* __restrict__ labcol,
        float* __restrict__ partial, float* __restrict__ lab, int Mpad) {
    __shared__ __align__(16) __bf16 Bp[64 * 512];   // 64 KB, fragment-major
    const int t = threadIdx.x;
    const int strip = blockIdx.x;
    const int c0 = strip * 64;
    const int branch = (c0 >= V) ? 1 : 0;

    // ---- stage W2 strip fp32 [512][64000] -> Bpack bf16
    {
        const int col = t & 63;
        const int ni = col >> 4, lncol = col & 15;
        const int kb0 = (t >> 6) * 8;
        for (int r = 0; r < 8; r++) {
            int kb = kb0 + r * 64;
            int ks = kb >> 5, qk = (kb >> 3) & 3;
            float v[8];
#pragma unroll
            for (int j = 0; j < 8; j++)
                v[j] = __builtin_nontemporal_load(w2 + (size_t)(kb + j) * N2 + c0 + col);
            bf16x8 o;
#pragma unroll
            for (int j = 0; j < 8; j++) o[j] = (__bf16)v[j];
            *(bf16x8*)&Bp[(size_t)(((ks * 4 + ni) * 64 + qk * 16 + lncol)) * 8] = o;
        }
    }
    __syncthreads();

    const int wave = t >> 6, lane = t & 63;
    const int q = lane >> 4, ln = lane & 15;
    const int* labB = labcol + branch * Mpad;

    float bvl2[4];
#pragma unroll
    for (int ni = 0; ni < 4; ni++) bvl2[ni] = b2[c0 + ni * 16 + ln] * LOG2E;

    const int npanels = Mpad >> 6;
    for (int p = wave; p < npanels; p += 8) {
        const __bf16* base = Apack + apack_chunk(p, 0, 0) + lane * 8;

        f32x4 acc[4][4] = {};
        bf16x8 afc[4], afn[4];
#pragma unroll
        for (int mi = 0; mi < 4; mi++)
            afc[mi] = *(const bf16x8*)(base + mi * 512);
#pragma unroll 1
        for (int ks = 0; ks < 16; ks++) {
            if (ks < 15) {
#pragma unroll
                for (int mi = 0; mi < 4; mi++)
                    afn[mi] = *(const bf16x8*)(base + (size_t)(ks + 1) * 2048 + mi * 512);
            }
            bf16x8 bf[4];
#pragma unroll
            for (int ni = 0; ni < 4; ni++)
                bf[ni] = *(const bf16x8*)&Bp[(size_t)(ks * 4 + ni) * 512 + lane * 8];
#pragma unroll
            for (int mi = 0; mi < 4; mi++)
#pragma unroll
                for (int ni = 0; ni < 4; ni++)
                    acc[mi][ni] = MFMA16(afc[mi], bf[ni], acc[mi][ni]);
#pragma unroll
            for (int mi = 0; mi < 4; mi++) afc[mi] = afn[mi];
        }

        // issue the hit-test load now; consumed after the exp2 stretch
        int myl = labB[p * 64 + lane];

        // ---- exp2-rowsum epilogue (bias folded into fma)
        float rowsum[4][4];
#pragma unroll
        for (int mi = 0; mi < 4; mi++)
#pragma unroll
            for (int r = 0; r < 4; r++) rowsum[mi][r] = 0.0f;
#pragma unroll
        for (int ni = 0; ni < 4; ni++) {
            const float bl2 = bvl2[ni];
#pragma unroll
            for (int mi = 0; mi < 4; mi++)
#pragma unroll
                for (int r = 0; r < 4; r++)
                    rowsum[mi][r] += __builtin_exp2f(__builtin_fmaf(acc[mi][ni][r], LOG2E, bl2));
        }

        // ---- rare label path: only if this panel contains a label column
        if (__any((unsigned)(myl - c0) < 64u)) {
#pragma unroll
            for (int ni = 0; ni < 4; ni++) {
                const int gcol = c0 + ni * 16 + ln;
                const float bv = b2[gcol];
#pragma unroll
                for (int mi = 0; mi < 4; mi++)
#pragma unroll
                    for (int r = 0; r < 4; r++) {
                        int row = p * 64 + mi * 16 + q * 4 + r;
                        if (gcol == labB[row]) {
                            lab[row * 2 + branch] = acc[mi][ni][r] + bv;
                        }
                    }
            }
        }

        // reduce over the 16 column-lanes (lane bits 0..3)
#pragma unroll
        for (int mi = 0; mi < 4; mi++)
#pragma unroll
            for (int r = 0; r < 4; r++) {
                float s = rowsum[mi][r];
                s += __shfl_xor(s, 1);
                s += __shfl_xor(s, 2);
                s += __shfl_xor(s, 4);
                s += __shfl_xor(s, 8);
                rowsum[mi][r] = s;
            }
        // per-lane row gather: lane l wants row l = mi*16 + q*4 + r; value
        // lives in lanes with q-src = (l>>2)&3 at register rowsum[l>>4][l&3].
        float mine = 0.0f;
        const int srcl = ((lane >> 2) & 3) * 16;
#pragma unroll
        for (int mi2 = 0; mi2 < 4; mi2++)
#pragma unroll
            for (int r2 = 0; r2 < 4; r2++) {
                float tv = __shfl(rowsum[mi2][r2], srcl);
                if ((lane >> 4) == mi2 && (lane & 3) == r2) mine = tv;
            }
        partial[(size_t)strip * Mpad + p * 64 + lane] = mine;
    }
}

// ---------------------------------------------------------------------------
// Fused final: block per (64-row panel, branch). 4 waves split the branch's
// 500 strips (125 each), coalesced 256 B reads, LDS combine, then wave 0
// computes nll = log(sumexp) - lab, weights, reduces, atomicAdd into out.
// ---------------------------------------------------------------------------
__global__ __launch_bounds__(256) void final_kernel(
        const float* __restrict__ partial, const float* __restrict__ lab,
        float* __restrict__ out, int M, int Mpad) {
    __shared__ float red[4][64];
    const int br = blockIdx.x & 1;
    const int m0 = (blockIdx.x >> 1) * 64;
    const int wave = threadIdx.x >> 6, lane = threadIdx.x & 63;
    const int s0 = br * (NSTRIP / 2) + wave * (NSTRIP / 8);
    float s = 0.0f;
#pragma unroll 5
    for (int i = 0; i < NSTRIP / 8; i++)
        s += partial[(size_t)(s0 + i) * Mpad + m0 + lane];
    red[wave][lane] = s;
    __syncthreads();
    if (wave == 0) {
        float tot = red[0][lane] + red[1][lane] + red[2][lane] + red[3][lane];
        int m = m0 + lane;
        float acc = 0.0f;
        if (m < M)
            acc = (br ? 0.25f : 1.0f) * (logf(tot) - lab[m * 2 + br]);
        acc += __shfl_xor(acc, 32);
        acc += __shfl_xor(acc, 16);
        acc += __shfl_xor(acc, 8);
        acc += __shfl_xor(acc, 4);
        acc += __shfl_xor(acc, 2);
        acc += __shfl_xor(acc, 1);
        if (lane == 0) atomicAdd(out, acc / (float)(2 * M));
    }
}

// ---------------------------------------------------------------------------
extern "C" void kernel_launch(void* const* d_in, const int* in_sizes, int n_in,
                              void* d_out, int out_size, void* d_ws, size_t ws_size,
                              hipStream_t stream) {
    const float* fwd = (const float*)d_in[0];
    const float* bwd = (const float*)d_in[1];
    const int*   seq = (const int*)d_in[2];
    const int*   fi  = (const int*)d_in[3];
    const int*   bi  = (const int*)d_in[4];
    const float* w1  = (const float*)d_in[5];
    const float* b1  = (const float*)d_in[6];
    const float* w2  = (const float*)d_in[7];
    const float* b2  = (const float*)d_in[8];
    float* out = (float*)d_out;

    const int N    = in_sizes[3];              // 1303
    const int M    = Bsz * N;                  // 2606
    const int Mpad = ((M + 255) / 256) * 256;  // 2816

    // workspace layout (16B-aligned slices)
    char* ws = (char*)d_ws;
    __bf16* A1    = (__bf16*)(ws);                                   // Mpad*1024
    __bf16* W1T   = (__bf16*)(ws + (size_t)Mpad * K1 * 2);           // 512*1024
    __bf16* Apack = (__bf16*)((char*)W1T + (size_t)N1 * K1 * 2);     // Mpad*512
    float*  partial = (float*)((char*)Apack + (size_t)Mpad * N1 * 2);// NSTRIP*Mpad
    float*  lab     = (float*)((char*)partial + (size_t)NSTRIP * Mpad * 4); // Mpad*2
    int*    labcol  = (int*)((char*)lab + (size_t)Mpad * 2 * 4);     // 2*Mpad

    // 1. fused prep: gather+cast (+labcol) and w1 transpose
    {
        int G1 = Mpad * (K1 / 8) / 256;        // gather blocks
        prep_kernel<<<G1 + 128, 256, 0, stream>>>(
            fwd, bwd, fi, bi, seq, w1, A1, W1T, labcol, N, M, Mpad, G1);
    }
    // 2. zero the output accumulator
    hipMemsetAsync(out, 0, sizeof(float), stream);
    // 3. GEMM1 -> Apack (fragment-major H)
    gemm1_kernel<<<dim3(N1 / 128, Mpad / 128), 256, 0, stream>>>(A1, W1T, b1, Apack, K1);
    // 4. GEMM2 persistent strips -> per-strip partial rowsums + labels
    gemm2_kernel<<<NSTRIP, 512, 0, stream>>>(Apack, w2, b2, labcol, partial, lab, Mpad);
    // 5. fused final: strip-reduce + NLL + weighted mean -> out
    final_kernel<<<(Mpad / 64) * 2, 256, 0, stream>>>(partial, lab, out, M, Mpad);
}

// Round 7
// 436.432 us; speedup vs baseline: 1.1372x; 1.0141x over previous
//
#include <hip/hip_runtime.h>

// ---------------------------------------------------------------------------
// BeliefStateWrapper: gather(fi,bi) -> Linear(1024->512)+LeakyReLU ->
// Linear(512->64000) -> per-branch log_softmax NLL -> weighted mean (scalar).
//
// R7: gemm2 restored to the R4-verbatim schedule (202 us, spill-free: lc
// loads -> merged label/exp loop -> shuffle reduce; any reorder spills at
// the 64-arch-VGPR cap -- measured R5/R6). Prep kernel deleted: gemm1 now
// gathers fwd/bwd rows via fi/bi directly into its A-tile and reads w1 fp32
// transposed into its B-tile (w1 is L2-resident), and computes labcol as a
// side-task. 4 launches total.
// ---------------------------------------------------------------------------

typedef __bf16 bf16x8 __attribute__((ext_vector_type(8)));
typedef __bf16 bf16x4 __attribute__((ext_vector_type(4)));
typedef float f32x4  __attribute__((ext_vector_type(4)));

#define MFMA16(a, b, c) __builtin_amdgcn_mfma_f32_16x16x32_bf16(a, b, c, 0, 0, 0)

static constexpr int Bsz   = 2;
static constexpr int L     = 512;
static constexpr int D     = 512;
static constexpr int V     = 32000;
static constexpr int K1    = 2 * D;      // 1024
static constexpr int N1    = D;          // 512
static constexpr int K2    = D;          // 512
static constexpr int N2    = 2 * V;      // 64000
static constexpr int NSTRIP = N2 / 64;   // 1000 strips (500 per branch)

// Apack chunk base (bf16 elems) for (panel, ks, mi); chunk = 64 lanes x 8
// bf16 = 512 elems = 1 KB. Lane l holds A[panel*64+mi*16+(l&15)]
// [ks*32+(l>>4)*8 .. +7].
__device__ __host__ inline size_t apack_chunk(int panel, int ks, int mi) {
    return (((size_t)panel * 16 + ks) * 4 + mi) * 512;
}

// ---------------------------------------------------------------------------
// GEMM1 (fused prep): Apack = pack(leaky_relu(gather(fwd,bwd,fi,bi) @ W1 + b1)).
// 128x128 tile, 4 waves (2x2), 16x16x32 MFMA, BK=32.
//  - A-tile staged straight from fwd/bwd via per-row offsets (gather fused);
//  - B-tile staged from w1 fp32 [k][n] with an LDS transpose (w1 ~2 MB,
//    L2-resident; each n-panel re-read 22x = 45 MB from L2, cheap);
//  - labcol side-task on the blockIdx.y==0 row of blocks;
//  - epilogue round-trips C through LDS -> coalesced Apack stores.
// ---------------------------------------------------------------------------
__global__ __launch_bounds__(256) void gemm1_kernel(
        const float* __restrict__ fwd, const float* __restrict__ bwd,
        const int* __restrict__ fi, const int* __restrict__ bi,
        const int* __restrict__ seq, const float* __restrict__ w1,
        const float* __restrict__ b1, __bf16* __restrict__ Apack,
        int* __restrict__ labcol, int N, int M, int Mpad) {
    __shared__ __align__(16) __bf16 At[128][40];
    __shared__ __align__(16) __bf16 Bl[128][40];
    __shared__ __align__(16) __bf16 Cld[128][136];
    __shared__ int offF[128];   // element offset of row in fwd (k<512 half)
    __shared__ int offB[128];   // element offset of row in bwd (k>=512 half)
    const int t = threadIdx.x;
    const int by = blockIdx.y, bx = blockIdx.x;
    const int m0 = by * 128, n0 = bx * 128;

    // ---- labcol side-task (blocks in row by==0 cover all entries)
    if (by == 0) {
        for (int i = bx * 256 + t; i < 2 * Mpad; i += 4 * 256) {
            int m = i >> 1, br = i & 1;
            if (m >= M) labcol[i] = -1;
            else {
                int b = m / N, n = m - b * N;
                int tok = br ? seq[b * L + bi[n]] : seq[b * L + fi[n]];
                labcol[i] = br * V + tok;
            }
        }
    }
    // ---- per-row gather offsets
    if (t < 128) {
        int m = m0 + t;
        int mc = (m < M) ? m : 0;          // pad rows read row 0 (harmless)
        int b = mc / N, n = mc - b * N;
        offF[t] = (b * L + fi[n]) * D;
        offB[t] = (b * L + bi[n]) * D;
    }
    __syncthreads();

    const int srow = t >> 2, schunk = (t & 3) * 8;
    const int wave = t >> 6, lane = t & 63;
    const int wrow = (wave >> 1) * 64, wcol = (wave & 1) * 64;
    const int q = lane >> 4, ln = lane & 15;
    const int bnn = (t & 31) * 4, bkk = t >> 5;     // B-staging coords

    f32x4 acc[4][4] = {};
    for (int k0 = 0; k0 < K1; k0 += 32) {
        __syncthreads();
        // A-tile: 2 rows/thread, 8 fp32 -> bf16x8 each
        {
            const float* p0;
            const float* p1;
            if (k0 < D) {
                p0 = fwd + offF[srow]      + k0 + schunk;
                p1 = fwd + offF[srow + 64] + k0 + schunk;
            } else {
                p0 = bwd + offB[srow]      + (k0 - D) + schunk;
                p1 = bwd + offB[srow + 64] + (k0 - D) + schunk;
            }
            float4 a0 = *(const float4*)(p0), a1 = *(const float4*)(p0 + 4);
            float4 c0v = *(const float4*)(p1), c1 = *(const float4*)(p1 + 4);
            bf16x8 o0, o1;
            o0[0] = (__bf16)a0.x; o0[1] = (__bf16)a0.y; o0[2] = (__bf16)a0.z; o0[3] = (__bf16)a0.w;
            o0[4] = (__bf16)a1.x; o0[5] = (__bf16)a1.y; o0[6] = (__bf16)a1.z; o0[7] = (__bf16)a1.w;
            o1[0] = (__bf16)c0v.x; o1[1] = (__bf16)c0v.y; o1[2] = (__bf16)c0v.z; o1[3] = (__bf16)c0v.w;
            o1[4] = (__bf16)c1.x; o1[5] = (__bf16)c1.y; o1[6] = (__bf16)c1.z; o1[7] = (__bf16)c1.w;
            *(bf16x8*)&At[srow][schunk]      = o0;
            *(bf16x8*)&At[srow + 64][schunk] = o1;
        }
        // B-tile: w1 fp32 [k][n] -> Bl[n][k] transposed (scalar LDS writes)
#pragma unroll
        for (int j = 0; j < 4; j++) {
            int kk = bkk + j * 8;
            float4 w = *(const float4*)(w1 + (size_t)(k0 + kk) * N1 + n0 + bnn);
            Bl[bnn + 0][kk] = (__bf16)w.x;
            Bl[bnn + 1][kk] = (__bf16)w.y;
            Bl[bnn + 2][kk] = (__bf16)w.z;
            Bl[bnn + 3][kk] = (__bf16)w.w;
        }
        __syncthreads();
        bf16x8 af[4], bfr[4];
        for (int i = 0; i < 4; i++) af[i]  = *(const bf16x8*)&At[wrow + i * 16 + ln][q * 8];
        for (int i = 0; i < 4; i++) bfr[i] = *(const bf16x8*)&Bl[wcol + i * 16 + ln][q * 8];
        for (int mi = 0; mi < 4; mi++)
            for (int ni = 0; ni < 4; ni++)
                acc[mi][ni] = MFMA16(af[mi], bfr[ni], acc[mi][ni]);
    }
    // bias + leaky -> LDS C tile
    for (int ni = 0; ni < 4; ni++) {
        int gcol = n0 + wcol + ni * 16 + ln;
        float bv = b1[gcol];
        for (int mi = 0; mi < 4; mi++)
            for (int r = 0; r < 4; r++) {
                float v = acc[mi][ni][r] + bv;
                v = v > 0.0f ? v : 0.01f * v;
                Cld[wrow + mi * 16 + q * 4 + r][wcol + ni * 16 + ln] = (__bf16)v;
            }
    }
    __syncthreads();
    // pack out: 32 chunks (pl 0..1, ksl 0..3, mi 0..3), wave w -> c = w+4i
    for (int i = 0; i < 8; i++) {
        int c   = wave + 4 * i;
        int pl  = c >> 4, ksl = (c >> 2) & 3, mi = c & 3;
        int row = pl * 64 + mi * 16 + (lane & 15);
        int col = ksl * 32 + (lane >> 4) * 8;
        bf16x8 v = *(const bf16x8*)&Cld[row][col];
        size_t base = apack_chunk(2 * by + pl, 4 * bx + ksl, mi);
        *(bf16x8*)(Apack + base + lane * 8) = v;
    }
}

// ---------------------------------------------------------------------------
// GEMM2 (persistent 64-col strip, 512 threads = 8 waves, 2 blocks/CU) --
// R4-VERBATIM schedule (measured 202 us, spill-free; do not reorder the
// epilogue: lc loads -> merged label/exp loop -> reduce).  W2 strip staged
// once fp32->bf16 into fragment-major LDS "Bpack" (conflict-free b128;
// non-temporal loads protect Apack's L2 residency).  A frags from L2 with
// one-k-step prefetch.
// ---------------------------------------------------------------------------
__global__ __launch_bounds__(512, 4) void gemm2_kernel(
        const __bf16* __restrict__ Apack, const float* __restrict__ w2,
        const float* __restrict__ b2, const int* __restrict__ labcol,
        float* __restrict__ partial, float* __restrict__ lab, int Mpad) {
    __shared__ __align__(16) __bf16 Bp[64 * 512];   // 64 KB, fragment-major
    const int t = threadIdx.x;
    const int strip = blockIdx.x;
    const int c0 = strip * 64;
    const int branch = (c0 >= V) ? 1 : 0;

    // ---- stage W2 strip fp32 [512][64000] -> Bpack bf16
    {
        const int col = t & 63;
        const int ni = col >> 4, lncol = col & 15;
        const int kb0 = (t >> 6) * 8;
        for (int r = 0; r < 8; r++) {
            int kb = kb0 + r * 64;
            int ks = kb >> 5, qk = (kb >> 3) & 3;
            float v[8];
#pragma unroll
            for (int j = 0; j < 8; j++)
                v[j] = __builtin_nontemporal_load(w2 + (size_t)(kb + j) * N2 + c0 + col);
            bf16x8 o;
#pragma unroll
            for (int j = 0; j < 8; j++) o[j] = (__bf16)v[j];
            *(bf16x8*)&Bp[(size_t)(((ks * 4 + ni) * 64 + qk * 16 + lncol)) * 8] = o;
        }
    }
    __syncthreads();

    const int wave = t >> 6, lane = t & 63;
    const int q = lane >> 4, ln = lane & 15;

    float bvn[4];
#pragma unroll
    for (int ni = 0; ni < 4; ni++) bvn[ni] = b2[c0 + ni * 16 + ln];

    const int npanels = Mpad >> 6;
    for (int p = wave; p < npanels; p += 8) {
        const __bf16* base = Apack + apack_chunk(p, 0, 0) + lane * 8;

        f32x4 acc[4][4] = {};
        bf16x8 afc[4], afn[4];
#pragma unroll
        for (int mi = 0; mi < 4; mi++)
            afc[mi] = *(const bf16x8*)(base + mi * 512);
#pragma unroll 1
        for (int ks = 0; ks < 16; ks++) {
            if (ks < 15) {
#pragma unroll
                for (int mi = 0; mi < 4; mi++)
                    afn[mi] = *(const bf16x8*)(base + (size_t)(ks + 1) * 2048 + mi * 512);
            }
            bf16x8 bf[4];
#pragma unroll
            for (int ni = 0; ni < 4; ni++)
                bf[ni] = *(const bf16x8*)&Bp[(size_t)(ks * 4 + ni) * 512 + lane * 8];
#pragma unroll
            for (int mi = 0; mi < 4; mi++)
#pragma unroll
                for (int ni = 0; ni < 4; ni++)
                    acc[mi][ni] = MFMA16(afc[mi], bf[ni], acc[mi][ni]);
#pragma unroll
            for (int mi = 0; mi < 4; mi++) afc[mi] = afn[mi];
        }

        // ---- epilogue for this panel (R4 order)
        int lc[4][4];
#pragma unroll
        for (int mi = 0; mi < 4; mi++)
#pragma unroll
            for (int r = 0; r < 4; r++)
                lc[mi][r] = labcol[(p * 64 + mi * 16 + q * 4 + r) * 2 + branch];

        float rowsum[4][4];
#pragma unroll
        for (int mi = 0; mi < 4; mi++)
#pragma unroll
            for (int r = 0; r < 4; r++) rowsum[mi][r] = 0.0f;

#pragma unroll
        for (int ni = 0; ni < 4; ni++) {
            const int gcol = c0 + ni * 16 + ln;
            const float bv = bvn[ni];
#pragma unroll
            for (int mi = 0; mi < 4; mi++)
#pragma unroll
                for (int r = 0; r < 4; r++) {
                    float v = acc[mi][ni][r] + bv;
                    rowsum[mi][r] += __expf(v);
                    if (gcol == lc[mi][r]) {
                        int gm = p * 64 + mi * 16 + q * 4 + r;
                        lab[gm * 2 + branch] = v;
                    }
                }
        }
        // reduce over the 16 column-lanes (lane bits 0..3)
#pragma unroll
        for (int mi = 0; mi < 4; mi++)
#pragma unroll
            for (int r = 0; r < 4; r++) {
                float s = rowsum[mi][r];
                s += __shfl_xor(s, 1);
                s += __shfl_xor(s, 2);
                s += __shfl_xor(s, 4);
                s += __shfl_xor(s, 8);
                rowsum[mi][r] = s;
            }
        // per-lane row gather: lane l wants row l = mi*16 + q*4 + r; value
        // lives in lanes with q-src = (l>>2)&3 at register rowsum[l>>4][l&3].
        float mine = 0.0f;
        const int srcl = ((lane >> 2) & 3) * 16;
#pragma unroll
        for (int mi2 = 0; mi2 < 4; mi2++)
#pragma unroll
            for (int r2 = 0; r2 < 4; r2++) {
                float tv = __shfl(rowsum[mi2][r2], srcl);
                if ((lane >> 4) == mi2 && (lane & 3) == r2) mine = tv;
            }
        partial[(size_t)strip * Mpad + p * 64 + lane] = mine;
    }
}

// ---------------------------------------------------------------------------
// Fused final: block per (64-row panel, branch). 4 waves split the branch's
// 500 strips (125 each), coalesced 256 B reads, LDS combine, then wave 0
// computes nll = log(sumexp) - lab, weights, reduces, atomicAdd into out.
// ---------------------------------------------------------------------------
__global__ __launch_bounds__(256) void final_kernel(
        const float* __restrict__ partial, const float* __restrict__ lab,
        float* __restrict__ out, int M, int Mpad) {
    __shared__ float red[4][64];
    const int br = blockIdx.x & 1;
    const int m0 = (blockIdx.x >> 1) * 64;
    const int wave = threadIdx.x >> 6, lane = threadIdx.x & 63;
    const int s0 = br * (NSTRIP / 2) + wave * (NSTRIP / 8);
    float s = 0.0f;
#pragma unroll 5
    for (int i = 0; i < NSTRIP / 8; i++)
        s += partial[(size_t)(s0 + i) * Mpad + m0 + lane];
    red[wave][lane] = s;
    __syncthreads();
    if (wave == 0) {
        float tot = red[0][lane] + red[1][lane] + red[2][lane] + red[3][lane];
        int m = m0 + lane;
        float acc = 0.0f;
        if (m < M)
            acc = (br ? 0.25f : 1.0f) * (logf(tot) - lab[m * 2 + br]);
        acc += __shfl_xor(acc, 32);
        acc += __shfl_xor(acc, 16);
        acc += __shfl_xor(acc, 8);
        acc += __shfl_xor(acc, 4);
        acc += __shfl_xor(acc, 2);
        acc += __shfl_xor(acc, 1);
        if (lane == 0) atomicAdd(out, acc / (float)(2 * M));
    }
}

// ---------------------------------------------------------------------------
extern "C" void kernel_launch(void* const* d_in, const int* in_sizes, int n_in,
                              void* d_out, int out_size, void* d_ws, size_t ws_size,
                              hipStream_t stream) {
    const float* fwd = (const float*)d_in[0];
    const float* bwd = (const float*)d_in[1];
    const int*   seq = (const int*)d_in[2];
    const int*   fi  = (const int*)d_in[3];
    const int*   bi  = (const int*)d_in[4];
    const float* w1  = (const float*)d_in[5];
    const float* b1  = (const float*)d_in[6];
    const float* w2  = (const float*)d_in[7];
    const float* b2  = (const float*)d_in[8];
    float* out = (float*)d_out;

    const int N    = in_sizes[3];              // 1303
    const int M    = Bsz * N;                  // 2606
    const int Mpad = ((M + 255) / 256) * 256;  // 2816

    // workspace layout (16B-aligned slices)
    char* ws = (char*)d_ws;
    __bf16* Apack   = (__bf16*)(ws);                                  // Mpad*512
    float*  partial = (float*)((char*)Apack + (size_t)Mpad * N1 * 2); // NSTRIP*Mpad
    float*  lab     = (float*)((char*)partial + (size_t)NSTRIP * Mpad * 4); // Mpad*2
    int*    labcol  = (int*)((char*)lab + (size_t)Mpad * 2 * 4);      // Mpad*2

    // 1. zero the output accumulator
    hipMemsetAsync(out, 0, sizeof(float), stream);
    // 2. GEMM1 (fused gather + w1-transpose + labcol) -> Apack
    gemm1_kernel<<<dim3(N1 / 128, Mpad / 128), 256, 0, stream>>>(
        fwd, bwd, fi, bi, seq, w1, b1, Apack, labcol, N, M, Mpad);
    // 3. GEMM2 persistent strips -> per-strip partial rowsums + labels
    gemm2_kernel<<<NSTRIP, 512, 0, stream>>>(Apack, w2, b2, labcol, partial, lab, Mpad);
    // 4. fused final: strip-reduce + NLL + weighted mean -> out
    final_kernel<<<(Mpad / 64) * 2, 256, 0, stream>>>(partial, lab, out, M, Mpad);
}

// Round 8
// 404.991 us; speedup vs baseline: 1.2255x; 1.0776x over previous
//
#include <hip/hip_runtime.h>

// ---------------------------------------------------------------------------
// BeliefStateWrapper: gather(fi,bi) -> Linear(1024->512)+LeakyReLU ->
// Linear(512->64000) -> per-branch log_softmax NLL -> weighted mean (scalar).
//
// R8: recombination of measured-best halves. Prep is a SEPARATE kernel
// (R6-style: gather+cast, w1 transpose, labcol) -- fusing it into gemm1's
// K-loop cost ~50 us (R7). gemm2 is the R4-VERBATIM schedule (199 us,
// spill-free at the 64-arch-VGPR cap; epilogue order lc->merged exp/label->
// reduce must not change -- R5/R6 both spilled on reorder). Parallel final
// reduce from R6.
// ---------------------------------------------------------------------------

typedef __bf16 bf16x8 __attribute__((ext_vector_type(8)));
typedef __bf16 bf16x4 __attribute__((ext_vector_type(4)));
typedef float f32x4  __attribute__((ext_vector_type(4)));

#define MFMA16(a, b, c) __builtin_amdgcn_mfma_f32_16x16x32_bf16(a, b, c, 0, 0, 0)

static constexpr int Bsz   = 2;
static constexpr int L     = 512;
static constexpr int D     = 512;
static constexpr int V     = 32000;
static constexpr int K1    = 2 * D;      // 1024
static constexpr int N1    = D;          // 512
static constexpr int K2    = D;          // 512
static constexpr int N2    = 2 * V;      // 64000
static constexpr int NSTRIP = N2 / 64;   // 1000 strips (500 per branch)

// Apack chunk base (bf16 elems) for (panel, ks, mi); chunk = 64 lanes x 8
// bf16 = 512 elems = 1 KB. Lane l holds A[panel*64+mi*16+(l&15)]
// [ks*32+(l>>4)*8 .. +7].
__device__ __host__ inline size_t apack_chunk(int panel, int ks, int mi) {
    return (((size_t)panel * 16 + ks) * 4 + mi) * 512;
}

// ---------------------------------------------------------------------------
// prep kernel: blocks [0, G1) do gather+cast (+labcol side-task, interleaved
// labcol[m*2+br] layout); blocks [G1, G1+128) transpose+cast w1 -> W1T.
// ---------------------------------------------------------------------------
__global__ void prep_kernel(const float* __restrict__ fwd,
                            const float* __restrict__ bwd,
                            const int* __restrict__ fi,
                            const int* __restrict__ bi,
                            const int* __restrict__ seq,
                            const float* __restrict__ w1,
                            __bf16* __restrict__ A1,
                            __bf16* __restrict__ W1T,
                            int* __restrict__ labcol,
                            int N, int M, int Mpad, int G1) {
    __shared__ __align__(16) __bf16 tile[64][68];
    if ((int)blockIdx.x >= G1) {
        // ---- w1 transpose part: bid -> (bx in [0,8), by in [0,16))
        int bid = blockIdx.x - G1;
        int bx = bid & 7, by = bid >> 3;
        int t  = threadIdx.x;
        int tx = t & 15, ty = t >> 4;
        int n0 = bx * 64, k0 = by * 64;
        for (int i = 0; i < 4; i++) {
            int k = k0 + ty + 16 * i;
            float4 v = *(const float4*)(w1 + (size_t)k * N1 + n0 + tx * 4);
            tile[tx * 4 + 0][ty + 16 * i] = (__bf16)v.x;
            tile[tx * 4 + 1][ty + 16 * i] = (__bf16)v.y;
            tile[tx * 4 + 2][ty + 16 * i] = (__bf16)v.z;
            tile[tx * 4 + 3][ty + 16 * i] = (__bf16)v.w;
        }
        __syncthreads();
        for (int i = 0; i < 4; i++) {
            int n = n0 + ty + 16 * i;
            bf16x4 o;
            o[0] = tile[ty + 16 * i][tx * 4 + 0];
            o[1] = tile[ty + 16 * i][tx * 4 + 1];
            o[2] = tile[ty + 16 * i][tx * 4 + 2];
            o[3] = tile[ty + 16 * i][tx * 4 + 3];
            *(bf16x4*)(W1T + (size_t)n * K1 + k0 + tx * 4) = o;
        }
        return;
    }
    int t = blockIdx.x * 256 + threadIdx.x;          // one thread = 8 elems
    // side-task: label columns, interleaved labcol[m*2+br]
    if (t < Mpad * 2) {
        int m = t >> 1, br = t & 1;
        if (m >= M) labcol[m * 2 + br] = -1;
        else {
            int b = m / N, n = m - b * N;
            int tok = br ? seq[b * L + bi[n]] : seq[b * L + fi[n]];
            labcol[m * 2 + br] = br * V + tok;
        }
    }
    int total = Mpad * (K1 / 8);
    if (t >= total) return;
    int m  = t >> 7;              // / (1024/8)
    int c8 = (t & 127) * 8;
    bf16x8 out;
    if (m < M) {
        int b = m / N;
        int n = m - b * N;
        const float* src;
        if (c8 < D) src = fwd + ((size_t)(b * L + fi[n])) * D + c8;
        else        src = bwd + ((size_t)(b * L + bi[n])) * D + (c8 - D);
        float4 v0 = *(const float4*)(src);
        float4 v1 = *(const float4*)(src + 4);
        out[0] = (__bf16)v0.x; out[1] = (__bf16)v0.y;
        out[2] = (__bf16)v0.z; out[3] = (__bf16)v0.w;
        out[4] = (__bf16)v1.x; out[5] = (__bf16)v1.y;
        out[6] = (__bf16)v1.z; out[7] = (__bf16)v1.w;
    } else {
        for (int j = 0; j < 8; j++) out[j] = (__bf16)0.0f;
    }
    *(bf16x8*)(A1 + (size_t)m * K1 + c8) = out;
}

// ---------------------------------------------------------------------------
// GEMM1: H = leaky_relu(A1 @ W1 + b1), emitted in Apack fragment-major
// layout.  128x128 tile, 4 waves (2x2), 16x16x32 MFMA, BK=32.  Epilogue
// round-trips C through LDS so the Apack stores are fully coalesced.
// ---------------------------------------------------------------------------
__global__ __launch_bounds__(256) void gemm1_kernel(
        const __bf16* __restrict__ A, const __bf16* __restrict__ Bt,
        const float* __restrict__ bias, __bf16* __restrict__ Apack, int K) {
    __shared__ __align__(16) __bf16 At[128][40];
    __shared__ __align__(16) __bf16 Bl[128][40];
    __shared__ __align__(16) __bf16 Cld[128][136];
    const int t = threadIdx.x;
    const int by = blockIdx.y, bx = blockIdx.x;
    const int m0 = by * 128, n0 = bx * 128;
    const int srow = t >> 2, schunk = (t & 3) * 8;
    const int wave = t >> 6, lane = t & 63;
    const int wrow = (wave >> 1) * 64, wcol = (wave & 1) * 64;
    const int q = lane >> 4, ln = lane & 15;

    f32x4 acc[4][4] = {};
    for (int k0 = 0; k0 < K; k0 += 32) {
        __syncthreads();
        *(bf16x8*)&At[srow][schunk]      = *(const bf16x8*)(A  + (size_t)(m0 + srow)      * K + k0 + schunk);
        *(bf16x8*)&At[srow + 64][schunk] = *(const bf16x8*)(A  + (size_t)(m0 + srow + 64) * K + k0 + schunk);
        *(bf16x8*)&Bl[srow][schunk]      = *(const bf16x8*)(Bt + (size_t)(n0 + srow)      * K + k0 + schunk);
        *(bf16x8*)&Bl[srow + 64][schunk] = *(const bf16x8*)(Bt + (size_t)(n0 + srow + 64) * K + k0 + schunk);
        __syncthreads();
        bf16x8 af[4], bfr[4];
        for (int i = 0; i < 4; i++) af[i]  = *(const bf16x8*)&At[wrow + i * 16 + ln][q * 8];
        for (int i = 0; i < 4; i++) bfr[i] = *(const bf16x8*)&Bl[wcol + i * 16 + ln][q * 8];
        for (int mi = 0; mi < 4; mi++)
            for (int ni = 0; ni < 4; ni++)
                acc[mi][ni] = MFMA16(af[mi], bfr[ni], acc[mi][ni]);
    }
    // bias + leaky -> LDS C tile
    for (int ni = 0; ni < 4; ni++) {
        int gcol = n0 + wcol + ni * 16 + ln;
        float bv = bias[gcol];
        for (int mi = 0; mi < 4; mi++)
            for (int r = 0; r < 4; r++) {
                float v = acc[mi][ni][r] + bv;
                v = v > 0.0f ? v : 0.01f * v;
                Cld[wrow + mi * 16 + q * 4 + r][wcol + ni * 16 + ln] = (__bf16)v;
            }
    }
    __syncthreads();
    // pack out: 32 chunks (pl 0..1, ksl 0..3, mi 0..3), wave w -> c = w+4i
    for (int i = 0; i < 8; i++) {
        int c   = wave + 4 * i;
        int pl  = c >> 4, ksl = (c >> 2) & 3, mi = c & 3;
        int row = pl * 64 + mi * 16 + (lane & 15);
        int col = ksl * 32 + (lane >> 4) * 8;
        bf16x8 v = *(const bf16x8*)&Cld[row][col];
        size_t base = apack_chunk(2 * by + pl, 4 * bx + ksl, mi);
        *(bf16x8*)(Apack + base + lane * 8) = v;
    }
}

// ---------------------------------------------------------------------------
// GEMM2 (persistent 64-col strip, 512 threads = 8 waves, 2 blocks/CU) --
// R4-VERBATIM schedule (measured 199-202 us, spill-free; do not reorder the
// epilogue: lc loads -> merged label/exp loop -> reduce).  W2 strip staged
// once fp32->bf16 into fragment-major LDS "Bpack" (conflict-free b128;
// non-temporal loads protect Apack's L2 residency).  A frags from L2 with
// one-k-step prefetch.
// ---------------------------------------------------------------------------
__global__ __launch_bounds__(512, 4) void gemm2_kernel(
        const __bf16* __restrict__ Apack, const float* __restrict__ w2,
        const float* __restrict__ b2, const int* __restrict__ labcol,
        float* __restrict__ partial, float* __restrict__ lab, int Mpad) {
    __shared__ __align__(16) __bf16 Bp[64 * 512];   // 64 KB, fragment-major
    const int t = threadIdx.x;
    const int strip = blockIdx.x;
    const int c0 = strip * 64;
    const int branch = (c0 >= V) ? 1 : 0;

    // ---- stage W2 strip fp32 [512][64000] -> Bpack bf16
    {
        const int col = t & 63;
        const int ni = col >> 4, lncol = col & 15;
        const int kb0 = (t >> 6) * 8;
        for (int r = 0; r < 8; r++) {
            int kb = kb0 + r * 64;
            int ks = kb >> 5, qk = (kb >> 3) & 3;
            float v[8];
#pragma unroll
            for (int j = 0; j < 8; j++)
                v[j] = __builtin_nontemporal_load(w2 + (size_t)(kb + j) * N2 + c0 + col);
            bf16x8 o;
#pragma unroll
            for (int j = 0; j < 8; j++) o[j] = (__bf16)v[j];
            *(bf16x8*)&Bp[(size_t)(((ks * 4 + ni) * 64 + qk * 16 + lncol)) * 8] = o;
        }
    }
    __syncthreads();

    const int wave = t >> 6, lane = t & 63;
    const int q = lane >> 4, ln = lane & 15;

    float bvn[4];
#pragma unroll
    for (int ni = 0; ni < 4; ni++) bvn[ni] = b2[c0 + ni * 16 + ln];

    const int npanels = Mpad >> 6;
    for (int p = wave; p < npanels; p += 8) {
        const __bf16* base = Apack + apack_chunk(p, 0, 0) + lane * 8;

        f32x4 acc[4][4] = {};
        bf16x8 afc[4], afn[4];
#pragma unroll
        for (int mi = 0; mi < 4; mi++)
            afc[mi] = *(const bf16x8*)(base + mi * 512);
#pragma unroll 1
        for (int ks = 0; ks < 16; ks++) {
            if (ks < 15) {
#pragma unroll
                for (int mi = 0; mi < 4; mi++)
                    afn[mi] = *(const bf16x8*)(base + (size_t)(ks + 1) * 2048 + mi * 512);
            }
            bf16x8 bf[4];
#pragma unroll
            for (int ni = 0; ni < 4; ni++)
                bf[ni] = *(const bf16x8*)&Bp[(size_t)(ks * 4 + ni) * 512 + lane * 8];
#pragma unroll
            for (int mi = 0; mi < 4; mi++)
#pragma unroll
                for (int ni = 0; ni < 4; ni++)
                    acc[mi][ni] = MFMA16(afc[mi], bf[ni], acc[mi][ni]);
#pragma unroll
            for (int mi = 0; mi < 4; mi++) afc[mi] = afn[mi];
        }

        // ---- epilogue for this panel (R4 order)
        int lc[4][4];
#pragma unroll
        for (int mi = 0; mi < 4; mi++)
#pragma unroll
            for (int r = 0; r < 4; r++)
                lc[mi][r] = labcol[(p * 64 + mi * 16 + q * 4 + r) * 2 + branch];

        float rowsum[4][4];
#pragma unroll
        for (int mi = 0; mi < 4; mi++)
#pragma unroll
            for (int r = 0; r < 4; r++) rowsum[mi][r] = 0.0f;

#pragma unroll
        for (int ni = 0; ni < 4; ni++) {
            const int gcol = c0 + ni * 16 + ln;
            const float bv = bvn[ni];
#pragma unroll
            for (int mi = 0; mi < 4; mi++)
#pragma unroll
                for (int r = 0; r < 4; r++) {
                    float v = acc[mi][ni][r] + bv;
                    rowsum[mi][r] += __expf(v);
                    if (gcol == lc[mi][r]) {
                        int gm = p * 64 + mi * 16 + q * 4 + r;
                        lab[gm * 2 + branch] = v;
                    }
                }
        }
        // reduce over the 16 column-lanes (lane bits 0..3)
#pragma unroll
        for (int mi = 0; mi < 4; mi++)
#pragma unroll
            for (int r = 0; r < 4; r++) {
                float s = rowsum[mi][r];
                s += __shfl_xor(s, 1);
                s += __shfl_xor(s, 2);
                s += __shfl_xor(s, 4);
                s += __shfl_xor(s, 8);
                rowsum[mi][r] = s;
            }
        // per-lane row gather: lane l wants row l = mi*16 + q*4 + r; value
        // lives in lanes with q-src = (l>>2)&3 at register rowsum[l>>4][l&3].
        float mine = 0.0f;
        const int srcl = ((lane >> 2) & 3) * 16;
#pragma unroll
        for (int mi2 = 0; mi2 < 4; mi2++)
#pragma unroll
            for (int r2 = 0; r2 < 4; r2++) {
                float tv = __shfl(rowsum[mi2][r2], srcl);
                if ((lane >> 4) == mi2 && (lane & 3) == r2) mine = tv;
            }
        partial[(size_t)strip * Mpad + p * 64 + lane] = mine;
    }
}

// ---------------------------------------------------------------------------
// Fused final: block per (64-row panel, branch). 4 waves split the branch's
// 500 strips (125 each), coalesced 256 B reads, LDS combine, then wave 0
// computes nll = log(sumexp) - lab, weights, reduces, atomicAdd into out.
// ---------------------------------------------------------------------------
__global__ __launch_bounds__(256) void final_kernel(
        const float* __restrict__ partial, const float* __restrict__ lab,
        float* __restrict__ out, int M, int Mpad) {
    __shared__ float red[4][64];
    const int br = blockIdx.x & 1;
    const int m0 = (blockIdx.x >> 1) * 64;
    const int wave = threadIdx.x >> 6, lane = threadIdx.x & 63;
    const int s0 = br * (NSTRIP / 2) + wave * (NSTRIP / 8);
    float s = 0.0f;
#pragma unroll 5
    for (int i = 0; i < NSTRIP / 8; i++)
        s += partial[(size_t)(s0 + i) * Mpad + m0 + lane];
    red[wave][lane] = s;
    __syncthreads();
    if (wave == 0) {
        float tot = red[0][lane] + red[1][lane] + red[2][lane] + red[3][lane];
        int m = m0 + lane;
        float acc = 0.0f;
        if (m < M)
            acc = (br ? 0.25f : 1.0f) * (logf(tot) - lab[m * 2 + br]);
        acc += __shfl_xor(acc, 32);
        acc += __shfl_xor(acc, 16);
        acc += __shfl_xor(acc, 8);
        acc += __shfl_xor(acc, 4);
        acc += __shfl_xor(acc, 2);
        acc += __shfl_xor(acc, 1);
        if (lane == 0) atomicAdd(out, acc / (float)(2 * M));
    }
}

// ---------------------------------------------------------------------------
extern "C" void kernel_launch(void* const* d_in, const int* in_sizes, int n_in,
                              void* d_out, int out_size, void* d_ws, size_t ws_size,
                              hipStream_t stream) {
    const float* fwd = (const float*)d_in[0];
    const float* bwd = (const float*)d_in[1];
    const int*   seq = (const int*)d_in[2];
    const int*   fi  = (const int*)d_in[3];
    const int*   bi  = (const int*)d_in[4];
    const float* w1  = (const float*)d_in[5];
    const float* b1  = (const float*)d_in[6];
    const float* w2  = (const float*)d_in[7];
    const float* b2  = (const float*)d_in[8];
    float* out = (float*)d_out;

    const int N    = in_sizes[3];              // 1303
    const int M    = Bsz * N;                  // 2606
    const int Mpad = ((M + 255) / 256) * 256;  // 2816

    // workspace layout (16B-aligned slices)
    char* ws = (char*)d_ws;
    __bf16* A1    = (__bf16*)(ws);                                   // Mpad*1024
    __bf16* W1T   = (__bf16*)(ws + (size_t)Mpad * K1 * 2);           // 512*1024
    __bf16* Apack = (__bf16*)((char*)W1T + (size_t)N1 * K1 * 2);     // Mpad*512
    float*  partial = (float*)((char*)Apack + (size_t)Mpad * N1 * 2);// NSTRIP*Mpad
    float*  lab     = (float*)((char*)partial + (size_t)NSTRIP * Mpad * 4); // Mpad*2
    int*    labcol  = (int*)((char*)lab + (size_t)Mpad * 2 * 4);     // Mpad*2

    // 1. fused prep: gather+cast (+labcol interleaved) and w1 transpose
    {
        int G1 = Mpad * (K1 / 8) / 256;        // gather blocks
        prep_kernel<<<G1 + 128, 256, 0, stream>>>(
            fwd, bwd, fi, bi, seq, w1, A1, W1T, labcol, N, M, Mpad, G1);
    }
    // 2. zero the output accumulator
    hipMemsetAsync(out, 0, sizeof(float), stream);
    // 3. GEMM1 -> Apack (fragment-major H)
    gemm1_kernel<<<dim3(N1 / 128, Mpad / 128), 256, 0, stream>>>(A1, W1T, b1, Apack, K1);
    // 4. GEMM2 persistent strips -> per-strip partial rowsums + labels
    gemm2_kernel<<<NSTRIP, 512, 0, stream>>>(Apack, w2, b2, labcol, partial, lab, Mpad);
    // 5. fused final: strip-reduce + NLL + weighted mean -> out
    final_kernel<<<(Mpad / 64) * 2, 256, 0, stream>>>(partial, lab, out, M, Mpad);
}